// Round 7
// baseline (1281.266 us; speedup 1.0000x reference)
//
#include <hip/hip_runtime.h>

// DRNet scan: 256 wgs x 512 threads (1 block/CU, 2 waves/SIMD); each wg owns
// 16 batch rows, iterates 256 steps locally. 6-term 3-level-bf16 MFMA split
// (proven absmax 2.0). R7 vs R6 (1397us steady, spill-bound):
//  - amdgpu_waves_per_eu(2,2): pins allocator at 2 waves/EU -> 256-reg budget.
//    (R6: compiler targeted 4 waves/EU = 128 regs and spilled the 192-reg W
//    fragments -> 47MB FETCH + 92MB WRITE of scratch per dispatch.)
//  - 4 accumulators (R4 mapping) -> MFMA dep distance 4, not 2.
//  - A-level-grouped MFMA order -> 1 A-level live (4 regs) instead of 3 (12).

#define TSTEPS 256
#define HDIM   256
#define ROWS   16
#define LSTR   264            // shorts per tile row (pad 8)
#define TILE   (ROWS * LSTR)  // 4224 shorts = 8448 B per level
#define XSTR   260

typedef __attribute__((ext_vector_type(8))) short short8;
typedef __attribute__((ext_vector_type(4))) float float4v;
typedef __bf16 bf16x8 __attribute__((ext_vector_type(8)));

struct U2 { unsigned x, y; };

__device__ __forceinline__ void tfround(unsigned &x0, unsigned &x1, const int r) {
  x0 += x1;
  x1 = __builtin_rotateleft32(x1, r);
  x1 ^= x0;
}

// Threefry-2x32, 20 rounds (Random123 / JAX threefry2x32_p)
__device__ __forceinline__ U2 threefry(unsigned k0, unsigned k1, unsigned x0, unsigned x1) {
  unsigned k2 = k0 ^ k1 ^ 0x1BD11BDAu;
  x0 += k0; x1 += k1;
  tfround(x0,x1,13); tfround(x0,x1,15); tfround(x0,x1,26); tfround(x0,x1,6);
  x0 += k1; x1 += k2 + 1u;
  tfround(x0,x1,17); tfround(x0,x1,29); tfround(x0,x1,16); tfround(x0,x1,24);
  x0 += k2; x1 += k0 + 2u;
  tfround(x0,x1,13); tfround(x0,x1,15); tfround(x0,x1,26); tfround(x0,x1,6);
  x0 += k0; x1 += k1 + 3u;
  tfround(x0,x1,17); tfround(x0,x1,29); tfround(x0,x1,16); tfround(x0,x1,24);
  x0 += k1; x1 += k2 + 4u;
  tfround(x0,x1,13); tfround(x0,x1,15); tfround(x0,x1,26); tfround(x0,x1,6);
  x0 += k2; x1 += k0 + 5u;
  return {x0, x1};
}

// JAX uniform(lo=nextafter(-1,0), 1) -> sqrt(2)*erf_inv(u), XLA ErfInv32.
__device__ __forceinline__ float jax_normal_from_bits(unsigned bits) {
#pragma clang fp contract(off)
  const float LO = __builtin_bit_cast(float, 0xBF7FFFFFu); // nextafter(-1,0)
  float f = __builtin_bit_cast(float, (bits >> 9) | 0x3f800000u) - 1.0f;
  float u = fmaf(f, 2.0f, LO);
  u = fmaxf(u, LO);
  float t1 = u * u;             // rounded u^2 (as XLA's x*x)
  float s  = 1.0f - t1;         // Sterbenz-exact in the tail; unfused
  float w  = -0.6931471805599453f * __builtin_amdgcn_logf(s);
  float p;
  if (w < 5.0f) {
    float z = w - 2.5f;
    p = 2.81022636e-08f;
    p = fmaf(p, z, 3.43273939e-07f);
    p = fmaf(p, z, -3.5233877e-06f);
    p = fmaf(p, z, -4.39150654e-06f);
    p = fmaf(p, z, 0.00021858087f);
    p = fmaf(p, z, -0.00125372503f);
    p = fmaf(p, z, -0.00417768164f);
    p = fmaf(p, z, 0.246640727f);
    p = fmaf(p, z, 1.50140941f);
  } else {
    float z = sqrtf(w) - 3.0f;
    p = -0.000200214257f;
    p = fmaf(p, z, 0.000100950558f);
    p = fmaf(p, z, 0.00134934322f);
    p = fmaf(p, z, -0.00367342844f);
    p = fmaf(p, z, 0.00573950773f);
    p = fmaf(p, z, -0.0076224613f);
    p = fmaf(p, z, 0.00943887047f);
    p = fmaf(p, z, 1.00167406f);
    p = fmaf(p, z, 2.83297682f);
  }
  return 1.4142135623730951f * (p * u);
}

__device__ __forceinline__ unsigned short bf16r(float f) { // round-to-nearest-even
  unsigned u = __builtin_bit_cast(unsigned, f);
  return (unsigned short)((u + 0x7fffu + ((u >> 16) & 1u)) >> 16);
}
__device__ __forceinline__ float bf2f(unsigned short h) {
  return __builtin_bit_cast(float, ((unsigned)h) << 16);
}

__device__ __forceinline__ float4v mfma_bf16(short8 a, short8 b, float4v c) {
  return __builtin_amdgcn_mfma_f32_16x16x32_bf16(
      __builtin_bit_cast(bf16x8, a), __builtin_bit_cast(bf16x8, b), c, 0, 0, 0);
}

__global__ __launch_bounds__(512)
__attribute__((amdgpu_waves_per_eu(2, 2)))
void drnet_kernel(const float* __restrict__ flat_img,
                  const float* __restrict__ W_ih,
                  const float* __restrict__ W_hh,
                  const float* __restrict__ b_ih,
                  const float* __restrict__ b_hh,
                  float* __restrict__ out)
{
  __shared__ float    x_sh[ROWS * XSTR];
  __shared__ unsigned keys_sh[2 * TSTEPS];
  // merged latent store: [buf][level][tile] -> single base + imm offsets
  __shared__ short    lat6[2][3][TILE];

  const int tid  = threadIdx.x;
  const int wg   = blockIdx.x;
  const int wv   = tid >> 6;
  const int lane = tid & 63;
  const int q    = lane >> 4;
  const int c    = lane & 15;

  // partitionable split: key_t = threefry((0,42), (0,t))
  if (tid < TSTEPS) {
    U2 kk = threefry(0u, 42u, 0u, (unsigned)tid);
    keys_sh[2*tid]   = kk.x;
    keys_sh[2*tid+1] = kk.y;
  }

  { // stage x: rows [wg*16, wg*16+16) of flat_img
    int i = tid * 8;
    int m = i >> 8;
    const float4v* src = (const float4v*)(flat_img + (size_t)wg * (ROWS*TSTEPS) + i);
    float4v v0 = src[0], v1 = src[1];
    float* dst = &x_sh[m * XSTR + (i & 255)];
    *(float4v*)dst       = v0;
    *((float4v*)dst + 1) = v1;
  }

  { // zero ALL of lat6: 2*3*TILE shorts == 3*TILE ints
    int* p0 = (int*)&lat6[0][0][0];
    for (int i = tid; i < 3 * TILE; i += 512) p0[i] = 0;
  }

  // persistent W_hh fragments: 3-level bf16 split, 192 regs/lane.
  short8 Whi[2][8], Wmd[2][8], Wlo[2][8];
  float bias[2], wih[2];
  #pragma unroll
  for (int nt = 0; nt < 2; ++nt) {
    int g = wv*32 + nt*16 + c;
    bias[nt] = b_ih[g] + b_hh[g];
    wih[nt]  = W_ih[g];
    #pragma unroll
    for (int kk = 0; kk < 8; ++kk) {
      const float* wp = W_hh + g*HDIM + kk*32 + q*8;
      float4v w0 = *(const float4v*)wp;
      float4v w1 = *(const float4v*)(wp + 4);
      short8 h8, m8, l8;
      #pragma unroll
      for (int j2 = 0; j2 < 4; ++j2) {
        float f0 = w0[j2], f1 = w1[j2];
        unsigned short hb0 = bf16r(f0), hb1 = bf16r(f1);
        float r0 = f0 - bf2f(hb0), r1 = f1 - bf2f(hb1);
        unsigned short mb0 = bf16r(r0), mb1 = bf16r(r1);
        h8[j2] = (short)hb0; h8[j2+4] = (short)hb1;
        m8[j2] = (short)mb0; m8[j2+4] = (short)mb1;
        l8[j2]   = (short)bf16r(r0 - bf2f(mb0));
        l8[j2+4] = (short)bf16r(r1 - bf2f(mb1));
      }
      Whi[nt][kk] = h8; Wmd[nt][kk] = m8; Wlo[nt][kk] = l8;
    }
  }

  // fp32 master latent: lane owns rows q*4+r, cols wv*32+nt*16+c; idx = nt*4+r
  float lat[8];
  #pragma unroll
  for (int i = 0; i < 8; ++i) lat[i] = 0.0f;

  const unsigned jbase = ((unsigned)(wg*ROWS + q*4) << 8) + (unsigned)(wv*32 + c);
  const int aoff = c * LSTR + q * 8;              // A-frag read offset (shorts)
  const int woff = (q*4) * LSTR + wv*32 + c;      // write offset base (shorts)

  __syncthreads();

  for (int t = 0; t < TSTEPS; ++t) {
    unsigned kA = (unsigned)__builtin_amdgcn_readfirstlane((int)keys_sh[2*t]);
    unsigned kB = (unsigned)__builtin_amdgcn_readfirstlane((int)keys_sh[2*t+1]);

    // sigma_t: ts=256-t; a=(ts+1)/257; sigma=sqrt(a(1-a)); exactly 0 at t=0
    float tsf = (float)(TSTEPS - t);
    float a_t = (tsf + 1.0f) / 257.0f;
    float escale = 0.1f * sqrtf(a_t * (1.0f - a_t));

    const short* rb = &lat6[t & 1][0][aoff];        // + lv*TILE + kk*32 (imm)
    short*       wb = &lat6[(t + 1) & 1][0][woff];  // + lv*TILE + r*LSTR + nt*16

    // 4 accumulators (dep distance >=4). Term->acc mapping as R4 (absmax 2.0):
    //   aXa: AhWh + AlWh + AhWl ; aXb: AmWh + AhWm + AmWm
    float4v a0a = {0,0,0,0}, a0b = {0,0,0,0};
    float4v a1a = {0,0,0,0}, a1b = {0,0,0,0};
    // k-loop, A-level-grouped (one A-level live at a time) + interleaved RNG
    #pragma unroll
    for (int kk = 0; kk < 8; ++kk) {
      short8 ah = *(const short8*)(rb + 0*TILE + kk*32);
      a0a = mfma_bf16(ah, Whi[0][kk], a0a);
      a1a = mfma_bf16(ah, Whi[1][kk], a1a);
      a0b = mfma_bf16(ah, Wmd[0][kk], a0b);
      a1b = mfma_bf16(ah, Wmd[1][kk], a1b);
      a0a = mfma_bf16(ah, Wlo[0][kk], a0a);
      a1a = mfma_bf16(ah, Wlo[1][kk], a1a);
      short8 am = *(const short8*)(rb + 1*TILE + kk*32);
      a0b = mfma_bf16(am, Whi[0][kk], a0b);
      a1b = mfma_bf16(am, Whi[1][kk], a1b);
      short8 al = *(const short8*)(rb + 2*TILE + kk*32);
      a0a = mfma_bf16(al, Whi[0][kk], a0a);
      a1a = mfma_bf16(al, Whi[1][kk], a1a);
      a0b = mfma_bf16(am, Wmd[0][kk], a0b);
      a1b = mfma_bf16(am, Wmd[1][kk], a1b);
      // noise for element idx=kk (nt=kk>>2, r=kk&3): j = b*256 + g
      {
        unsigned j = jbase + (unsigned)((kk & 3)*256 + (kk >> 2)*16);
        U2 rr = threefry(kA, kB, 0u, j);
        float nrm = jax_normal_from_bits(rr.x ^ rr.y);
        lat[kk] = fmaf(escale, nrm, lat[kk]);  // in-place; escale=0 at t=0
      }
    }

    float xr[4];
    #pragma unroll
    for (int r = 0; r < 4; ++r) xr[r] = x_sh[(q*4 + r) * XSTR + t];

    #pragma unroll
    for (int nt = 0; nt < 2; ++nt) {
      #pragma unroll
      for (int r = 0; r < 4; ++r) {
        float d = nt ? (a1a[r] + a1b[r]) : (a0a[r] + a0b[r]);
        float pre = d + fmaf(xr[r], wih[nt], bias[nt]);
        // tanh with XLA clamp: |x| >= 7.90531111 -> +/-1 exactly
        float h;
        if (__builtin_fabsf(pre) >= 7.90531110763549805f) {
          h = pre > 0.0f ? 1.0f : -1.0f;
        } else {
          float e = __builtin_amdgcn_exp2f(pre * 2.8853900817779268f);
          h = fmaf(-2.0f, __builtin_amdgcn_rcpf(e + 1.0f), 1.0f);
        }
        float nl = lat[nt*4 + r] + xr[r] + h;   // noise already folded in
        lat[nt*4 + r] = nl;
        // 3-level bf16 store of new latent (imm-offset writes)
        unsigned short hb16 = bf16r(nl);
        float r1f = nl - bf2f(hb16);
        unsigned short mb16 = bf16r(r1f);
        unsigned short lb16 = bf16r(r1f - bf2f(mb16));
        short* wp = wb + r*LSTR + nt*16;
        wp[0*TILE] = (short)hb16;
        wp[1*TILE] = (short)mb16;
        wp[2*TILE] = (short)lb16;
      }
    }
    __syncthreads(); // single barrier/step (reads buf t&1, writes (t+1)&1)
  }

  #pragma unroll
  for (int nt = 0; nt < 2; ++nt) {
    #pragma unroll
    for (int r = 0; r < 4; ++r)
      out[jbase + (unsigned)(r*256 + nt*16)] = lat[nt*4 + r];
  }
}

extern "C" void kernel_launch(void* const* d_in, const int* in_sizes, int n_in,
                              void* d_out, int out_size, void* d_ws, size_t ws_size,
                              hipStream_t stream) {
  // inputs: [0]=T (int, =256), [1]=flat_img (4096x256 f32), [2]=W_ih (256x1),
  // [3]=W_hh (256x256), [4]=b_ih (256), [5]=b_hh (256)
  (void)in_sizes; (void)n_in; (void)out_size; (void)d_ws; (void)ws_size;
  const float* flat_img = (const float*)d_in[1];
  const float* W_ih     = (const float*)d_in[2];
  const float* W_hh     = (const float*)d_in[3];
  const float* b_ih     = (const float*)d_in[4];
  const float* b_hh     = (const float*)d_in[5];
  drnet_kernel<<<dim3(4096 / ROWS), dim3(512), 0, stream>>>(
      flat_img, W_ih, W_hh, b_ih, b_hh, (float*)d_out);
}

// Round 8
// 987.749 us; speedup vs baseline: 1.2972x; 1.2972x over previous
//
#include <hip/hip_runtime.h>

// DRNet scan, R8: 256 wgs x 1024 threads (16 waves; wave wv owns cols
// [wv*16,wv*16+16)); each wg owns 16 batch rows, runs all 256 steps locally.
// GEMM: mfma_f32_16x16x32_f16 with TWO-level fp16 split of latent and W_hh,
// residual level pre-scaled by 2^11 (keeps fp16 normal range) -> rep error
// 2^-24, same as the proven 6-term bf16 scheme (absmax 2.0) at HALF the
// MFMA count and HALF the W register bytes. W frags = 64 VGPRs/lane; total
// demand ~120 fits the 128-reg budget the allocator picks at 4 waves/EU ->
// no spills (R6/R7 lost ~2.5x to W-spill reload traffic: 50MB FETCH + 97MB
// WRITE of scratch). LDS padded to 84KB so only 1 block/CU fits -> LDS-
// allowed occupancy = exactly 4 waves/EU = launch_bounds min -> 128 regs.
// RNG: bit-exact JAX threefry2x32 partitionable + XLA ErfInv (proven).

#define TSTEPS 256
#define HDIM   256
#define ROWS   16
#define LSTR   264            // shorts per tile row (pad 8 -> 2-way aliasing, free)
#define TILE   (ROWS * LSTR)  // 4224 shorts = 8448 B per level
#define XSTR   260

typedef _Float16 half8 __attribute__((ext_vector_type(8)));
typedef __attribute__((ext_vector_type(4))) float float4v;

struct U2 { unsigned x, y; };

__device__ __forceinline__ void tfround(unsigned &x0, unsigned &x1, const int r) {
  x0 += x1;
  x1 = __builtin_rotateleft32(x1, r);
  x1 ^= x0;
}

// Threefry-2x32, 20 rounds (Random123 / JAX threefry2x32_p)
__device__ __forceinline__ U2 threefry(unsigned k0, unsigned k1, unsigned x0, unsigned x1) {
  unsigned k2 = k0 ^ k1 ^ 0x1BD11BDAu;
  x0 += k0; x1 += k1;
  tfround(x0,x1,13); tfround(x0,x1,15); tfround(x0,x1,26); tfround(x0,x1,6);
  x0 += k1; x1 += k2 + 1u;
  tfround(x0,x1,17); tfround(x0,x1,29); tfround(x0,x1,16); tfround(x0,x1,24);
  x0 += k2; x1 += k0 + 2u;
  tfround(x0,x1,13); tfround(x0,x1,15); tfround(x0,x1,26); tfround(x0,x1,6);
  x0 += k0; x1 += k1 + 3u;
  tfround(x0,x1,17); tfround(x0,x1,29); tfround(x0,x1,16); tfround(x0,x1,24);
  x0 += k1; x1 += k2 + 4u;
  tfround(x0,x1,13); tfround(x0,x1,15); tfround(x0,x1,26); tfround(x0,x1,6);
  x0 += k2; x1 += k0 + 5u;
  return {x0, x1};
}

// JAX uniform(lo=nextafter(-1,0), 1) -> sqrt(2)*erf_inv(u), XLA ErfInv32.
__device__ __forceinline__ float jax_normal_from_bits(unsigned bits) {
#pragma clang fp contract(off)
  const float LO = __builtin_bit_cast(float, 0xBF7FFFFFu); // nextafter(-1,0)
  float f = __builtin_bit_cast(float, (bits >> 9) | 0x3f800000u) - 1.0f;
  float u = fmaf(f, 2.0f, LO);
  u = fmaxf(u, LO);
  float t1 = u * u;             // rounded u^2 (as XLA's x*x)
  float s  = 1.0f - t1;         // Sterbenz-exact in the tail; unfused
  float w  = -0.6931471805599453f * __builtin_amdgcn_logf(s);
  float p;
  if (w < 5.0f) {
    float z = w - 2.5f;
    p = 2.81022636e-08f;
    p = fmaf(p, z, 3.43273939e-07f);
    p = fmaf(p, z, -3.5233877e-06f);
    p = fmaf(p, z, -4.39150654e-06f);
    p = fmaf(p, z, 0.00021858087f);
    p = fmaf(p, z, -0.00125372503f);
    p = fmaf(p, z, -0.00417768164f);
    p = fmaf(p, z, 0.246640727f);
    p = fmaf(p, z, 1.50140941f);
  } else {
    float z = sqrtf(w) - 3.0f;
    p = -0.000200214257f;
    p = fmaf(p, z, 0.000100950558f);
    p = fmaf(p, z, 0.00134934322f);
    p = fmaf(p, z, -0.00367342844f);
    p = fmaf(p, z, 0.00573950773f);
    p = fmaf(p, z, -0.0076224613f);
    p = fmaf(p, z, 0.00943887047f);
    p = fmaf(p, z, 1.00167406f);
    p = fmaf(p, z, 2.83297682f);
  }
  return 1.4142135623730951f * (p * u);
}

__device__ __forceinline__ float4v mfma_f16(half8 a, half8 b, float4v c) {
  return __builtin_amdgcn_mfma_f32_16x16x32_f16(a, b, c, 0, 0, 0);
}

__global__ __launch_bounds__(1024, 4)
void drnet_kernel(const float* __restrict__ flat_img,
                  const float* __restrict__ W_ih,
                  const float* __restrict__ W_hh,
                  const float* __restrict__ b_ih,
                  const float* __restrict__ b_hh,
                  float* __restrict__ out)
{
  // 86016 B > 81920 -> only 1 block/CU fits LDS -> occupancy exactly 4
  // waves/EU -> allocator budgets 128 VGPRs; demand ~120 -> no spills.
  __shared__ __align__(16) char lds_pool[86016];
  float*    x_sh    = (float*)lds_pool;                 // 16640 B
  unsigned* keys_sh = (unsigned*)(lds_pool + 16640);    // 2048 B
  short*    latp    = (short*)(lds_pool + 18688);       // 2 buf x 2 lv x TILE = 33792 B

  const int tid  = threadIdx.x;
  const int wg   = blockIdx.x;
  const int wv   = tid >> 6;     // 0..15: wave owns cols [wv*16, wv*16+16)
  const int lane = tid & 63;
  const int q    = lane >> 4;
  const int c    = lane & 15;

  // partitionable split: key_t = threefry((0,42), (0,t))
  if (tid < TSTEPS) {
    U2 kk = threefry(0u, 42u, 0u, (unsigned)tid);
    keys_sh[2*tid]   = kk.x;
    keys_sh[2*tid+1] = kk.y;
  }

  { // stage x: 4096 floats, one float4 per thread
    int i = tid * 4;
    int m = i >> 8;
    float4v v = *(const float4v*)(flat_img + (size_t)wg * (ROWS*TSTEPS) + i);
    *(float4v*)&x_sh[m * XSTR + (i & 255)] = v;
  }

  { // zero latent: 2*2*TILE shorts == 2*TILE ints
    int* p0 = (int*)latp;
    for (int i = tid; i < 2 * TILE; i += 1024) p0[i] = 0;
  }

  // persistent W_hh fragments: 2-level fp16 split, 64 VGPRs/lane.
  // B-frag: B[k=q*8+j][n=c] -> lane reads W_hh row g = wv*16+c.
  // Level-1 pre-scaled by 2^11 (exact pow2) -> normal fp16 range.
  half8 Wh[8], Wl[8];
  const int g = wv*16 + c;
  const float bias = b_ih[g] + b_hh[g];
  const float wih  = W_ih[g];
  #pragma unroll
  for (int kk = 0; kk < 8; ++kk) {
    const float* wp = W_hh + g*HDIM + kk*32 + q*8;
    float4v w0 = *(const float4v*)wp;
    float4v w1 = *(const float4v*)(wp + 4);
    half8 h8, l8;
    #pragma unroll
    for (int j2 = 0; j2 < 4; ++j2) {
      float f0 = w0[j2], f1 = w1[j2];
      _Float16 h0 = (_Float16)f0, h1 = (_Float16)f1;         // RNE
      _Float16 l0 = (_Float16)((f0 - (float)h0) * 2048.0f);  // exact residual
      _Float16 l1 = (_Float16)((f1 - (float)h1) * 2048.0f);
      h8[j2] = h0; h8[j2+4] = h1;
      l8[j2] = l0; l8[j2+4] = l1;
    }
    Wh[kk] = h8; Wl[kk] = l8;
  }

  // fp32 master latent: lane owns rows q*4+r (r<4), col g
  float lat[4] = {0.f, 0.f, 0.f, 0.f};

  const unsigned jbase = ((unsigned)(wg*ROWS + q*4) << 8) + (unsigned)g;
  const int aoff = c * LSTR + q * 8;          // A-frag: A[m=lane&15][k=q*8+j]
  const int woff = (q*4) * LSTR + wv*16 + c;  // write base (shorts)

  __syncthreads();

  for (int t = 0; t < TSTEPS; ++t) {
    unsigned kA = (unsigned)__builtin_amdgcn_readfirstlane((int)keys_sh[2*t]);
    unsigned kB = (unsigned)__builtin_amdgcn_readfirstlane((int)keys_sh[2*t+1]);

    // sigma_t: ts=256-t; a=(ts+1)/257; sigma=sqrt(a(1-a)); exactly 0 at t=0
    float tsf = (float)(TSTEPS - t);
    float a_t = (tsf + 1.0f) / 257.0f;
    float escale = 0.1f * sqrtf(a_t * (1.0f - a_t));

    const short* rb = latp + (t & 1) * (2*TILE) + aoff;
    short*       wb = latp + ((t + 1) & 1) * (2*TILE) + woff;

    // terms: AhWh -> aa ; (AlWh + AhWl) -> ab (both carry one 2^11 scale);
    // dropped AlWl ~2^-24 rel. d = aa + ab/2048.
    float4v aa = {0.f, 0.f, 0.f, 0.f};
    float4v ab = {0.f, 0.f, 0.f, 0.f};
    #pragma unroll
    for (int kk = 0; kk < 8; ++kk) {
      half8 ah = *(const half8*)(rb + 0*TILE + kk*32);
      half8 al = *(const half8*)(rb + 1*TILE + kk*32);
      aa = mfma_f16(ah, Wh[kk], aa);
      ab = mfma_f16(al, Wh[kk], ab);
      ab = mfma_f16(ah, Wl[kk], ab);
      if (kk < 4) { // noise for element r=kk: j = b*256+g, b = wg*16+q*4+kk
        unsigned j = jbase + (unsigned)(kk << 8);
        U2 rr = threefry(kA, kB, 0u, j);
        float nrm = jax_normal_from_bits(rr.x ^ rr.y);
        lat[kk] = fmaf(escale, nrm, lat[kk]);  // in-place; escale=0 at t=0
      }
    }

    float xr[4];
    #pragma unroll
    for (int r = 0; r < 4; ++r) xr[r] = x_sh[(q*4 + r) * XSTR + t];

    #pragma unroll
    for (int r = 0; r < 4; ++r) {
      float d = aa[r] + ab[r] * (1.0f / 2048.0f);
      float pre = d + fmaf(xr[r], wih, bias);
      // tanh with XLA clamp: |x| >= 7.90531111 -> +/-1 exactly
      float h;
      if (__builtin_fabsf(pre) >= 7.90531110763549805f) {
        h = pre > 0.0f ? 1.0f : -1.0f;
      } else {
        float e = __builtin_amdgcn_exp2f(pre * 2.8853900817779268f);
        h = fmaf(-2.0f, __builtin_amdgcn_rcpf(e + 1.0f), 1.0f);
      }
      float nl = lat[r] + xr[r] + h;   // noise already folded in
      lat[r] = nl;
      // 2-level fp16 store (level-1 scaled by 2^11)
      _Float16 hh = (_Float16)nl;                       // RNE
      _Float16 ll = (_Float16)((nl - (float)hh) * 2048.0f);
      short* wp = wb + r*LSTR;
      wp[0]    = __builtin_bit_cast(short, hh);
      wp[TILE] = __builtin_bit_cast(short, ll);
    }
    __syncthreads(); // single barrier/step (reads buf t&1, writes (t+1)&1)
  }

  #pragma unroll
  for (int r = 0; r < 4; ++r)
    out[jbase + (unsigned)(r << 8)] = lat[r];
}

extern "C" void kernel_launch(void* const* d_in, const int* in_sizes, int n_in,
                              void* d_out, int out_size, void* d_ws, size_t ws_size,
                              hipStream_t stream) {
  // inputs: [0]=T (int, =256), [1]=flat_img (4096x256 f32), [2]=W_ih (256x1),
  // [3]=W_hh (256x256), [4]=b_ih (256), [5]=b_hh (256)
  (void)in_sizes; (void)n_in; (void)out_size; (void)d_ws; (void)ws_size;
  const float* flat_img = (const float*)d_in[1];
  const float* W_ih     = (const float*)d_in[2];
  const float* W_hh     = (const float*)d_in[3];
  const float* b_ih     = (const float*)d_in[4];
  const float* b_hh     = (const float*)d_in[5];
  drnet_kernel<<<dim3(4096 / ROWS), dim3(1024), 0, stream>>>(
      flat_img, W_ih, W_hh, b_ih, b_hh, (float*)d_out);
}